// Round 10
// baseline (132.298 us; speedup 1.0000x reference)
//
#include <hip/hip_runtime.h>

// SSIM loss, R12b: resubmission of R12 (bench was an infra failure —
// "MI355X container failed twice", 4th occurrence; R1/R5/R7 had the identical
// signature and passed unchanged on resubmit). Re-audited: exact task cover
// (260 loads = 256 primary + 4 stragglers), all LDS/global bounds in range,
// Ht pad rows j=26..31 rewritten as exact zeros every iter (no stale bytes
// into MFMA), uniform barriers (8 iters all blocks), guarded loads.
//
// R12 design. R11 post-mortem: ssim_main ~39 us (below the 42us fill
// dispatches in top-5), all pipes <37% busy -> concurrency-starved at
// 4 blocks/CU (LDS 40.4KB). R12: halve the tile to 64x16.
//  - X[4][32][88] f16 (XP 104->88; alias 64*40=2560 <= 32*88=2816, HTP=40)
//    -> LDS 22.8KB -> 6 blocks/CU (24 waves, +50%), __launch_bounds__(256,6).
//  - grid = 1536 persistent blocks x 8 iters; bc = bcg + 6*it (bcg=b>>8).
//  - h-conv: 2 M-tiles, 8 MFMA; v-conv: ONE N-tile k=32, 4 MFMA.
//  - X pad rows 26..31 zero-stored EVERY iter (Ht alias corrupts them;
//    garbage -> f16 overflow -> inf*0 = NaN otherwise).
//  - staging: 260 load-tasks (26r x 10c8) = 1/thread + 4 stragglers (tid<4,
//    direct L2-hot load in phase A, short liveness) + 60 zero-pad tasks.
// Retained from R11: BAR_LGKM (lgkmcnt-only barrier, vmcnt never drained ->
// 1-deep register prefetch of the primary task rides across barriers),
// LDS g-table, one-k-step band frags, rs compensation, 4 planes (a,b,aa+bb,ab).

typedef __attribute__((ext_vector_type(2))) float  f32x2;
typedef __attribute__((ext_vector_type(4))) float  f32x4;
typedef __fp16 f16;
typedef __attribute__((ext_vector_type(2))) __fp16 h2v;
typedef __attribute__((ext_vector_type(4))) __fp16 h4;
typedef __attribute__((ext_vector_type(8))) __fp16 h8;

constexpr int IMG_H = 512;
constexpr int IMG_W = 512;
constexpr int PL    = IMG_H * IMG_W;
constexpr int NBC   = 48;
constexpr int TW    = 64;
constexpr int TH    = 16;
constexpr int NPERS = 1536;                // 6 blocks/CU x 256 CU
constexpr int ITERS = (IMG_W / TW) * (IMG_H / TH) * NBC / NPERS; // 8

constexpr int XP   = 88;                   // X pitch (halves), 44 dw
constexpr int XR   = 32;                   // X rows (26 data + 6 zero pad)
constexpr int XQS  = XR * XP;              // 2816 halves per plane
constexpr int HTP  = 40;                   // Ht pitch (halves), mult of 8
constexpr int HTQS = 64 * HTP;             // 2560 halves per plane
constexpr int SMEMH = 4 * XQS;             // 11264 halves = 22,528 B
static_assert(4 * HTQS <= SMEMH, "Ht must fit in X union");

constexpr float C1 = 1.0e-4f;
constexpr float C2 = 9.0e-4f;

#define BAR_LGKM() do {                                       \
    __builtin_amdgcn_sched_barrier(0);                        \
    asm volatile("s_waitcnt lgkmcnt(0)" ::: "memory");        \
    __builtin_amdgcn_s_barrier();                             \
    __builtin_amdgcn_sched_barrier(0);                        \
} while (0)

// Normalized gaussian g[d] = exp(-(d-5)^2/4.5)/sum, f32-rounded.
__device__ const float GW[11] = {
    0.00102838f, 0.00759876f, 0.03600077f, 0.10936070f, 0.21300553f,
    0.26601172f, 0.21300553f, 0.10936070f, 0.03600077f, 0.00759876f,
    0.00102838f};

__device__ __forceinline__ h8 ldfrag(const f16* __restrict__ gtab, int base) {
    h8 b;
#pragma unroll
    for (int i = 0; i < 8; ++i) b[i] = gtab[base + i];
    return b;
}

__device__ __forceinline__ void cvt_store(f16* __restrict__ smem, int o,
                                          const float4& a0f, const float4& a1f,
                                          const float4& b0f, const float4& b1f) {
    const f32x2* a0 = (const f32x2*)&a0f;
    const f32x2* a1 = (const f32x2*)&a1f;
    const f32x2* b0 = (const f32x2*)&b0f;
    const f32x2* b1 = (const f32x2*)&b1f;
    const f32x2 s0 = a0[0] * a0[0] + b0[0] * b0[0];
    const f32x2 s1 = a0[1] * a0[1] + b0[1] * b0[1];
    const f32x2 s2 = a1[0] * a1[0] + b1[0] * b1[0];
    const f32x2 s3 = a1[1] * a1[1] + b1[1] * b1[1];
    const f32x2 p0 = a0[0] * b0[0], p1 = a0[1] * b0[1];
    const f32x2 p2 = a1[0] * b1[0], p3 = a1[1] * b1[1];
    union { h2v h2[4]; h8 v; } uva, uvb, uss, uab;
    uva.h2[0] = __builtin_amdgcn_cvt_pkrtz(a0[0].x, a0[0].y);
    uva.h2[1] = __builtin_amdgcn_cvt_pkrtz(a0[1].x, a0[1].y);
    uva.h2[2] = __builtin_amdgcn_cvt_pkrtz(a1[0].x, a1[0].y);
    uva.h2[3] = __builtin_amdgcn_cvt_pkrtz(a1[1].x, a1[1].y);
    uvb.h2[0] = __builtin_amdgcn_cvt_pkrtz(b0[0].x, b0[0].y);
    uvb.h2[1] = __builtin_amdgcn_cvt_pkrtz(b0[1].x, b0[1].y);
    uvb.h2[2] = __builtin_amdgcn_cvt_pkrtz(b1[0].x, b1[0].y);
    uvb.h2[3] = __builtin_amdgcn_cvt_pkrtz(b1[1].x, b1[1].y);
    uss.h2[0] = __builtin_amdgcn_cvt_pkrtz(s0.x, s0.y);
    uss.h2[1] = __builtin_amdgcn_cvt_pkrtz(s1.x, s1.y);
    uss.h2[2] = __builtin_amdgcn_cvt_pkrtz(s2.x, s2.y);
    uss.h2[3] = __builtin_amdgcn_cvt_pkrtz(s3.x, s3.y);
    uab.h2[0] = __builtin_amdgcn_cvt_pkrtz(p0.x, p0.y);
    uab.h2[1] = __builtin_amdgcn_cvt_pkrtz(p1.x, p1.y);
    uab.h2[2] = __builtin_amdgcn_cvt_pkrtz(p2.x, p2.y);
    uab.h2[3] = __builtin_amdgcn_cvt_pkrtz(p3.x, p3.y);
    *(h8*)&smem[0 * XQS + o] = uva.v;
    *(h8*)&smem[1 * XQS + o] = uvb.v;
    *(h8*)&smem[2 * XQS + o] = uss.v;
    *(h8*)&smem[3 * XQS + o] = uab.v;
}

__global__ __launch_bounds__(64) void ssim_init(double* acc) {
    if (threadIdx.x == 0) acc[0] = 0.0;
}

__global__ __launch_bounds__(256, 6) void ssim_main(const float* __restrict__ sr,
                                                    const float* __restrict__ hr,
                                                    double* __restrict__ sink,
                                                    int mode) {
    __shared__ __align__(16) f16 smem[SMEMH];   // X[4][32][88] / Ht[4][64][40] alias
    __shared__ __align__(8)  f16 gtab[128];     // zero-padded weights, g at [66..76]
    __shared__ float wsums[4];

    const int tid  = threadIdx.x;
    const int w    = tid >> 6;
    const int lane = tid & 63;
    const int l15  = lane & 15;
    const int grp8 = (lane >> 4) << 3;
    const int grp4 = (lane >> 4) << 2;

    // tile (x,y) fixed; bc = bcg + 6*it
    const int bx  = blockIdx.x & 7;
    const int by  = (blockIdx.x >> 3) & 31;
    const int bcg = blockIdx.x >> 8;            // 0..5
    const int gr0 = by * TH - 5;
    const int gc0 = bx * TW - 8;

    const float* __restrict__ srp = sr + (size_t)bcg * PL;
    const float* __restrict__ hrp = hr + (size_t)bcg * PL;
    const size_t PSTEP = (size_t)6 * PL;

    // ---- primary staging task (1/thread): 260 load-tasks = 26r x 10c8 ----
    const int r0s = tid / 10, c0s = tid - 10 * r0s;   // tid<256 -> r0s<=25
    const int gr_0 = gr0 + r0s, gc_0 = gc0 + c0s * 8;
    const bool ok0 = ((unsigned)gr_0 < (unsigned)IMG_H) &
                     ((unsigned)gc_0 < (unsigned)IMG_W);
    const int off0 = gr_0 * IMG_W + gc_0;
    const int o0   = r0s * XP + c0s * 8;

    // ---- 4 straggler tasks (256..259): r=25, c8=6+tid; direct load in-loop ----
    const int cx   = 6 + tid;                   // valid for tid<4
    const int grx  = gr0 + 25, gcx = gc0 + cx * 8;
    const bool okx = (tid < 4) & ((unsigned)grx < (unsigned)IMG_H) &
                     ((unsigned)gcx < (unsigned)IMG_W);
    const int offx = grx * IMG_W + gcx;
    const int ox   = 25 * XP + cx * 8;

    // ---- zero-pad tasks: rows 26..31 (Ht alias corrupts them each iter) ----
    const int rz = 26 + tid / 10, cz = tid - 10 * (tid / 10);
    const int oz = rz * XP + cz * 8;            // used for tid<60

    // ---- g-table fill ----
    if (tid < 128) {
        const int d = tid - 66;
        float v = 0.f;
        if ((unsigned)d <= 10u) v = GW[d];
        gtab[tid] = (f16)v;
    }

    // ---- rs compensation (pure-constant f16 round-trip) ----
    float s16 = 0.f;
#pragma unroll
    for (int d = 0; d <= 10; ++d) s16 += (float)(f16)GW[d];
    const float rs = 1.0f / (s16 * s16);

    // ---- prologue: prefetch primary task of tile 0 (16 VGPR) ----
    float4 La0, La1, Lb0, Lb1;
    La0 = La1 = Lb0 = Lb1 = (float4){0.f, 0.f, 0.f, 0.f};
    if (ok0) {
        const float4* pa = (const float4*)&srp[off0];
        const float4* pb = (const float4*)&hrp[off0];
        La0 = pa[0]; La1 = pa[1]; Lb0 = pb[0]; Lb1 = pb[1];
    }
    __syncthreads();                            // gtab ready

    const h8 bh = ldfrag(gtab, 63 + grp8 - l15);   // h-conv: g[kl-l15-3]
    const h8 bv = ldfrag(gtab, 66 + grp8 - l15);   // v-conv: g[kl-l15]

    float local = 0.f;

    for (int it = 0; it < ITERS; ++it) {
        // ---- phase A: straggler direct loads (L2-hot: shared with y+1
        //      neighbor's halo), primary cvt, zero-pad stores ----
        if (tid < 4) {
            float4 ea0, ea1, eb0, eb1;
            ea0 = ea1 = eb0 = eb1 = (float4){0.f, 0.f, 0.f, 0.f};
            if (okx) {
                const float4* pa = (const float4*)&srp[offx];
                const float4* pb = (const float4*)&hrp[offx];
                ea0 = pa[0]; ea1 = pa[1]; eb0 = pb[0]; eb1 = pb[1];
            }
            cvt_store(smem, ox, ea0, ea1, eb0, eb1);
        }
        cvt_store(smem, o0, La0, La1, Lb0, Lb1);
        if (tid < 60) {
            const h8 z = {};
            *(h8*)&smem[0 * XQS + oz] = z;
            *(h8*)&smem[1 * XQS + oz] = z;
            *(h8*)&smem[2 * XQS + oz] = z;
            *(h8*)&smem[3 * XQS + oz] = z;
        }

        BAR_LGKM();                             // X ready (no vmcnt drain)

        // ---- prefetch next tile's primary task (rides across barriers) ----
        if (it < ITERS - 1) {
            srp += PSTEP; hrp += PSTEP;
            if (ok0) {
                const float4* pa = (const float4*)&srp[off0];
                const float4* pb = (const float4*)&hrp[off0];
                La0 = pa[0]; La1 = pa[1]; Lb0 = pb[0]; Lb1 = pb[1];
            }
        }
        __builtin_amdgcn_sched_barrier(0);

        // ---- h-conv: wave w owns out-cols 16w..16w+15; A k-offset 16w ----
        f32x4 acc[4][2] = {};                   // [plane][M-tile]
#pragma unroll
        for (int Mt = 0; Mt < 2; ++Mt) {
            const int arow = (16 * Mt + l15) * XP + 16 * w + grp8;
#pragma unroll
            for (int q = 0; q < 4; ++q) {
                const h8 af = *(const h8*)&smem[q * XQS + arow];
                acc[q][Mt] = __builtin_amdgcn_mfma_f32_16x16x32_f16(af, bh, acc[q][Mt], 0, 0, 0);
            }
        }

        BAR_LGKM();                             // X consumed; reuse as Ht

        // ---- transpose-store D1 -> Ht[4][64][40] f16 (j=0..31 all written) ----
#pragma unroll
        for (int q = 0; q < 4; ++q) {
#pragma unroll
            for (int Mt = 0; Mt < 2; ++Mt) {
                union { h2v h2[2]; h4 v; } u;
                u.h2[0] = __builtin_amdgcn_cvt_pkrtz(acc[q][Mt][0], acc[q][Mt][1]);
                u.h2[1] = __builtin_amdgcn_cvt_pkrtz(acc[q][Mt][2], acc[q][Mt][3]);
                *(h4*)&smem[q * HTQS + (16 * w + l15) * HTP + 16 * Mt + grp4] = u.v;
            }
        }

        // ---- v-conv: ONE N-tile (out rows 0..15), k=32; wave-own Ht cols ----
        f32x4 acc2[4] = {};
        const int abase = (16 * w + l15) * HTP + grp8;
#pragma unroll
        for (int q = 0; q < 4; ++q) {
            const h8 a0 = *(const h8*)&smem[q * HTQS + abase];
            acc2[q] = __builtin_amdgcn_mfma_f32_16x16x32_f16(a0, bv, acc2[q], 0, 0, 0);
        }

        // ---- SSIM map on D2 (4 px/thread: row=l15, col=16w+grp4+e) ----
        {
            const f32x4 m1 = acc2[0] * rs;
            const f32x4 m2 = acc2[1] * rs;
            const f32x4 S  = acc2[2] * rs;
            const f32x4 pp = acc2[3] * rs;
            const f32x4 mu1s = m1 * m1, mu2s = m2 * m2, mu12 = m1 * m2;
            const f32x4 sg12 = pp - mu12;
            const f32x4 sgs  = S - mu1s - mu2s;
            const f32x4 num = (2.f * mu12 + C1) * (2.f * sg12 + C2);
            const f32x4 den = (mu1s + mu2s + C1) * (sgs + C2) + 1e-12f;
#pragma unroll
            for (int e = 0; e < 4; ++e)
                local += num[e] * __builtin_amdgcn_rcpf(den[e]);
        }

        BAR_LGKM();                             // Ht consumed before next X store
    }

    // ---- block reduction ----
#pragma unroll
    for (int offr = 32; offr > 0; offr >>= 1)
        local += __shfl_down(local, offr, 64);
    if ((tid & 63) == 0) wsums[tid >> 6] = local;
    __syncthreads();
    if (tid == 0) {
        const double bsum = (double)(wsums[0] + wsums[1] + wsums[2] + wsums[3]);
        if (mode == 0) {
            sink[blockIdx.x] = bsum;
        } else {
            atomicAdd(sink, bsum);
        }
    }
}

__global__ __launch_bounds__(256) void ssim_finalize(const double* __restrict__ partial,
                                                     float* __restrict__ out, int count) {
    __shared__ double ws[4];
    double s = 0.0;
    for (int i = threadIdx.x; i < count; i += 256) s += partial[i];
#pragma unroll
    for (int off = 32; off > 0; off >>= 1)
        s += __shfl_down(s, off, 64);
    const int lane = threadIdx.x & 63, wave = threadIdx.x >> 6;
    if (lane == 0) ws[wave] = s;
    __syncthreads();
    if (threadIdx.x == 0) {
        const double tot = ws[0] + ws[1] + ws[2] + ws[3];
        const double n = (double)NBC * IMG_H * IMG_W;
        out[0] = (float)(1.0 - tot / n);
    }
}

extern "C" void kernel_launch(void* const* d_in, const int* in_sizes, int n_in,
                              void* d_out, int out_size, void* d_ws, size_t ws_size,
                              hipStream_t stream) {
    const float* sr = (const float*)d_in[0];
    const float* hr = (const float*)d_in[1];
    float* out = (float*)d_out;

    if (ws_size >= (size_t)NPERS * sizeof(double)) {
        double* partial = (double*)d_ws; // fully overwritten each call
        ssim_main<<<dim3(NPERS), dim3(256), 0, stream>>>(sr, hr, partial, 0);
        ssim_finalize<<<dim3(1), dim3(256), 0, stream>>>(partial, out, NPERS);
    } else {
        double* acc = (double*)d_ws;
        ssim_init<<<dim3(1), dim3(64), 0, stream>>>(acc);
        ssim_main<<<dim3(NPERS), dim3(256), 0, stream>>>(sr, hr, acc, 1);
        ssim_finalize<<<dim3(1), dim3(256), 0, stream>>>(acc, out, 1);
    }
}